// Round 11
// baseline (1718.902 us; speedup 1.0000x reference)
//
#include <hip/hip_runtime.h>
#include <math.h>

typedef unsigned long long u64;
typedef unsigned int u32;

#define NB 64
#define M21 ((1u << 21) - 1)

// key = (f32 bits of priority << 23) | edge index. Order-isomorphic to the
// reference's stable-argsort rank (p >= 0 -> bits value-monotone; index
// breaks ties exactly like stable argsort). E < 2^23.
__device__ __forceinline__ u64 mkkey(float p, int e) {
    return ((u64)__float_as_uint(p) << 23) | (unsigned)e;
}
__device__ __forceinline__ u64 umax64(u64 a, u64 b) { return a > b ? a : b; }

__global__ void k_sentinel(float* out, float v) {
    if (threadIdx.x == 0 && blockIdx.x == 0) out[0] = v;
}
__global__ void k_zero16(uint4* __restrict__ p, int n) {
    int i = blockIdx.x * blockDim.x + threadIdx.x;
    if (i < n) p[i] = make_uint4(0, 0, 0, 0);
}
__global__ void k_copyW(u64* __restrict__ dst, const u64* __restrict__ src, int n) {
    int i = blockIdx.x * blockDim.x + threadIdx.x;
    if (i < n) dst[i] = src[i];
}

// ---------------- bucket permutation (counting sort by x >> shift) ----------

__global__ void k_hist(const int2* __restrict__ edges, u32* __restrict__ bcnt,
                       int E, int shift) {
    __shared__ u32 lh[NB];
    int tid = threadIdx.x;
    if (tid < NB) lh[tid] = 0;
    __syncthreads();
    int e = blockIdx.x * blockDim.x + tid;
    if (e < E) atomicAdd(&lh[edges[e].x >> shift], 1u);
    __syncthreads();
    if (tid < NB && lh[tid]) atomicAdd(&bcnt[tid], lh[tid]);
}

__global__ void k_scan(const u32* __restrict__ bcnt, u32* __restrict__ bcur) {
    if (threadIdx.x == 0 && blockIdx.x == 0) {
        u32 run = 0;
        for (int i = 0; i < NB; ++i) { bcur[i] = run; run += bcnt[i]; }
    }
}

// LDS-aggregated scatter: block reserves a contiguous range per bucket.
__global__ void k_permute(const int2* __restrict__ edges, const float* __restrict__ pri,
                          u64* __restrict__ permA, u64* __restrict__ permB,
                          u32* __restrict__ bcur, int E, int shift) {
    __shared__ u32 lcnt[NB];
    __shared__ u32 lbase[NB];
    int tid = threadIdx.x;
    if (tid < NB) lcnt[tid] = 0;
    __syncthreads();
    int e = blockIdx.x * blockDim.x + tid;
    int b = 0; u32 my = 0; int2 ed;
    bool act = (e < E);
    if (act) { ed = edges[e]; b = ed.x >> shift; my = atomicAdd(&lcnt[b], 1u); }
    __syncthreads();
    if (tid < NB && lcnt[tid]) lbase[tid] = atomicAdd(&bcur[tid], lcnt[tid]);
    __syncthreads();
    if (act) {
        u32 pos = lbase[b] + my;
        permA[pos] = (u64)(u32)ed.x | ((u64)(u32)ed.y << 21);
        permB[pos] = mkkey(pri[e], e);
    }
}

// ---------------- permuted sweeps (x-side L2-localized) ---------------------

__global__ void k_scatter1_p(const u64* __restrict__ pa, const u64* __restrict__ pk,
                             u64* __restrict__ vert, int E) {
    int i = blockIdx.x * blockDim.x + threadIdx.x;
    if (i >= E) return;
    u64 a = pa[i];
    int x = (int)(a & M21), y = (int)((a >> 21) & M21);
    u64 k = pk[i];
    u64 va = vert[x], vb = vert[y];           // read-filter (monotone, safe)
    if (k > va) atomicMax(&vert[x], k);
    if (k > vb) atomicMax(&vert[y], k);
}

__global__ void k_fused_p(const u64* __restrict__ pa, const u64* __restrict__ vsrc,
                          u64* __restrict__ vdst, int E) {
    int i = blockIdx.x * blockDim.x + threadIdx.x;
    if (i >= E) return;
    u64 a = pa[i];
    int x = (int)(a & M21), y = (int)((a >> 21) & M21);
    u64 va = vsrc[x], vb = vsrc[y];
    u64 er = umax64(va, vb);
    if (er > va) atomicMax(&vdst[x], er);
    if (er > vb) atomicMax(&vdst[y], er);
}

// flags bit0 = connA (1 at c0), bit1 = markC. Matching -> plain stores.
__global__ void k_cand_p(const u64* __restrict__ pa, const u64* __restrict__ pk,
                         const u64* __restrict__ vert, unsigned char* __restrict__ flags,
                         unsigned char* __restrict__ candp, int E) {
    int i = blockIdx.x * blockDim.x + threadIdx.x;
    if (i >= E) return;
    u64 a = pa[i];
    int x = (int)(a & M21), y = (int)((a >> 21) & M21);
    u64 k = pk[i];
    u64 er = umax64(vert[x], vert[y]);
    bool c = (er == k) && ((k >> 23) != 0);   // pbits!=0 <=> p>0
    candp[i] = c ? 1 : 0;
    if (c) { flags[x] = 3; if (y != x) flags[y] = 2; }
}

__global__ void k_conn1_p(const u64* __restrict__ pa, const unsigned char* __restrict__ flags,
                          u32* __restrict__ pack, int E) {
    int i = blockIdx.x * blockDim.x + threadIdx.x;
    if (i >= E) return;
    u64 a = pa[i];
    int x = (int)(a & M21), y = (int)((a >> 21) & M21);
    u32 ec = (u32)(flags[x] & 1) + (u32)(flags[y] & 1);
    if (ec) { atomicAdd(&pack[x], ec); atomicAdd(&pack[y], ec); }
}

// round 2 into hi16; set-0 via markC bit at read. lo16 stable here.
__global__ void k_conn2_p(const u64* __restrict__ pa, const unsigned char* __restrict__ flags,
                          u32* __restrict__ pack, int E) {
    int i = blockIdx.x * blockDim.x + threadIdx.x;
    if (i >= E) return;
    u64 a = pa[i];
    int x = (int)(a & M21), y = (int)((a >> 21) & M21);
    unsigned char gx = flags[x], gy = flags[y];
    u32 fx = (gx & 2) ? 0u : ((u32)(gx & 1) + (pack[x] & 0xFFFFu));
    u32 fy = (gy & 2) ? 0u : ((u32)(gy & 1) + (pack[y] & 0xFFFFu));
    u32 ec = fx + fy;
    if (ec) { atomicAdd(&pack[x], ec << 16); atomicAdd(&pack[y], ec << 16); }
}

__global__ void k_collapse_p(const u64* __restrict__ pa, const unsigned char* __restrict__ candp,
                             const unsigned char* __restrict__ flags,
                             const u32* __restrict__ pack, const float* __restrict__ vin,
                             int* __restrict__ repl, float* __restrict__ vout, int E) {
    int i = blockIdx.x * blockDim.x + threadIdx.x;
    if (i >= E) return;
    if (!candp[i]) return;
    u64 a = pa[i];
    int x = (int)(a & M21), y = (int)((a >> 21) & M21);
    unsigned char gy = flags[y];
    u32 py = pack[y];
    u32 fy = (gy & 2) ? 0u : ((u32)(gy & 1) + (py & 0xFFFFu));
    u32 total = fy + (py >> 16);
    if (total <= 2) {
        repl[y] = x + 1;
        size_t bx = (size_t)x * 3, by = (size_t)y * 3;
#pragma unroll
        for (int j = 0; j < 3; ++j)
            vout[bx + j] = 0.5f * (vin[bx + j] + vin[by + j]);
    }
}

// ---------------- fallback scalar sweeps (R9-proven path) -------------------

__global__ void k_scatter1(const int2* __restrict__ edges, const float* __restrict__ pri,
                           u64* __restrict__ vert, int E) {
    int e = blockIdx.x * blockDim.x + threadIdx.x;
    if (e >= E) return;
    u64 k = mkkey(pri[e], e);
    int2 ed = edges[e];
    u64 a = vert[ed.x], b = vert[ed.y];
    if (k > a) atomicMax(&vert[ed.x], k);
    if (k > b) atomicMax(&vert[ed.y], k);
}
__global__ void k_fused(const int2* __restrict__ edges, const u64* __restrict__ vsrc,
                        u64* __restrict__ vdst, int E) {
    int e = blockIdx.x * blockDim.x + threadIdx.x;
    if (e >= E) return;
    int2 ed = edges[e];
    u64 a = vsrc[ed.x], b = vsrc[ed.y];
    u64 er = umax64(a, b);
    if (er > a) atomicMax(&vdst[ed.x], er);
    if (er > b) atomicMax(&vdst[ed.y], er);
}
__global__ void k_cand(const int2* __restrict__ edges, const float* __restrict__ pri,
                       const u64* __restrict__ vert, unsigned char* __restrict__ flags,
                       unsigned char* __restrict__ cand, int E) {
    int e = blockIdx.x * blockDim.x + threadIdx.x;
    if (e >= E) return;
    int2 ed = edges[e];
    u64 er = umax64(vert[ed.x], vert[ed.y]);
    float p = pri[e];
    bool c = (er == mkkey(p, e)) && (p > 0.0f);
    cand[e] = c ? 1 : 0;
    if (c) { flags[ed.x] = 3; if (ed.y != ed.x) flags[ed.y] = 2; }
}
__global__ void k_conn1(const int2* __restrict__ edges, const unsigned char* __restrict__ flags,
                        u32* __restrict__ pack, int E) {
    int e = blockIdx.x * blockDim.x + threadIdx.x;
    if (e >= E) return;
    int2 ed = edges[e];
    u32 ec = (u32)(flags[ed.x] & 1) + (u32)(flags[ed.y] & 1);
    if (ec) { atomicAdd(&pack[ed.x], ec); atomicAdd(&pack[ed.y], ec); }
}
__global__ void k_conn2(const int2* __restrict__ edges, const unsigned char* __restrict__ flags,
                        u32* __restrict__ pack, int E) {
    int e = blockIdx.x * blockDim.x + threadIdx.x;
    if (e >= E) return;
    int2 ed = edges[e];
    unsigned char gx = flags[ed.x], gy = flags[ed.y];
    u32 fx = (gx & 2) ? 0u : ((u32)(gx & 1) + (pack[ed.x] & 0xFFFFu));
    u32 fy = (gy & 2) ? 0u : ((u32)(gy & 1) + (pack[ed.y] & 0xFFFFu));
    u32 ec = fx + fy;
    if (ec) { atomicAdd(&pack[ed.x], ec << 16); atomicAdd(&pack[ed.y], ec << 16); }
}
__global__ void k_collapse(const int2* __restrict__ edges, const unsigned char* __restrict__ cand,
                           const unsigned char* __restrict__ flags,
                           const u32* __restrict__ pack, const float* __restrict__ vin,
                           int* __restrict__ repl, float* __restrict__ vout, int E) {
    int e = blockIdx.x * blockDim.x + threadIdx.x;
    if (e >= E) return;
    if (!cand[e]) return;
    int2 ed = edges[e];
    unsigned char gy = flags[ed.y];
    u32 py = pack[ed.y];
    u32 fy = (gy & 2) ? 0u : ((u32)(gy & 1) + (py & 0xFFFFu));
    u32 total = fy + (py >> 16);
    if (total <= 2) {
        repl[ed.y] = ed.x + 1;
        size_t bx = (size_t)ed.x * 3, by = (size_t)ed.y * 3;
#pragma unroll
        for (int j = 0; j < 3; ++j)
            vout[bx + j] = 0.5f * (vin[bx + j] + vin[by + j]);
    }
}

__global__ void k_faces(const int* __restrict__ faces, const int* __restrict__ repl,
                        float* __restrict__ fout, int F) {
    int i = blockIdx.x * blockDim.x + threadIdx.x;
    if (i >= F) return;
    size_t b = (size_t)i * 3;
    int a0 = faces[b + 0], a1 = faces[b + 1], a2 = faces[b + 2];
    int r0 = repl[a0]; if (r0) a0 = r0 - 1;
    int r1 = repl[a1]; if (r1) a1 = r1 - 1;
    int r2 = repl[a2]; if (r2) a2 = r2 - 1;
    if (a0 == a1 || a1 == a2 || a0 == a2) { a0 = 0; a1 = 0; a2 = 0; }
    fout[b + 0] = (float)a0;
    fout[b + 1] = (float)a1;
    fout[b + 2] = (float)a2;
}

extern "C" void kernel_launch(void* const* d_in, const int* in_sizes, int n_in,
                              void* d_out, int out_size, void* d_ws, size_t ws_size,
                              hipStream_t stream) {
    const int V = in_sizes[0] / 3;
    const int F = in_sizes[1] / 3;
    const int E = in_sizes[3];

    const float* vin  = (const float*)d_in[0];
    const int* faces  = (const int*)d_in[1];
    const int2* edges = (const int2*)d_in[2];
    const float* pri  = (const float*)d_in[3];

    float* vout = (float*)d_out;
    float* fout = vout + (size_t)V * 3;

    char* ws = (char*)d_ws;
    size_t off = 0;
    auto alloc = [&](size_t n) -> void* {
        void* p = ws + off;
        off = (off + n + 255) & ~(size_t)255;
        return p;
    };
    // zero span: bmeta, vertA, flags, pack, repl
    u32* bcnt            = (u32*)alloc(NB * 4);
    u32* bcur            = (u32*)alloc(NB * 4);
    u64* vertA           = (u64*)alloc((size_t)V * 8);
    unsigned char* flags = (unsigned char*)alloc((size_t)V);
    u32* pack            = (u32*)alloc((size_t)V * 4);
    int* repl            = (int*)alloc((size_t)V * 4);
    size_t zero_bytes = off;
    u64* vertB           = (u64*)alloc((size_t)V * 8);
    unsigned char* cand  = (unsigned char*)alloc((size_t)E + 4);
    size_t needed_base = off;
    u64* permA           = (u64*)alloc((size_t)E * 8);
    u64* permB           = (u64*)alloc((size_t)E * 8);
    size_t needed_ext = off;

    const int TB = 256;
    if (ws_size > 0 && ws_size < needed_base) {
        k_sentinel<<<1, 64, 0, stream>>>(vout, ldexpf(1.0f, (int)(ws_size >> 23)));
        return;
    }
    const bool use_perm = (ws_size >= needed_ext) && (V <= (1 << 21)) && (E < (1 << 23));

    const int gE = (E + TB - 1) / TB;
    const int gF = (F + TB - 1) / TB;
    const int gW = (V + TB - 1) / TB;
    const int nZ = (int)(zero_bytes / 16);
    const int gZ = (nZ + TB - 1) / TB;

    k_zero16<<<gZ, TB, 0, stream>>>((uint4*)ws, nZ);
    hipMemcpyAsync(d_out, d_in[0], (size_t)V * 3 * sizeof(float),
                   hipMemcpyDeviceToDevice, stream);

    if (use_perm) {
        int shift = 0;
        while (((V - 1) >> shift) >= NB) shift++;
        const int PT = 1024;
        const int gP = (E + PT - 1) / PT;
        k_hist   <<<gP, PT, 0, stream>>>(edges, bcnt, E, shift);
        k_scan   <<<1, 64, 0, stream>>>(bcnt, bcur);
        k_permute<<<gP, PT, 0, stream>>>(edges, pri, permA, permB, bcur, E, shift);

        k_scatter1_p<<<gE, TB, 0, stream>>>(permA, permB, vertA, E);
        k_copyW<<<gW, TB, 0, stream>>>(vertB, vertA, V);
        k_fused_p<<<gE, TB, 0, stream>>>(permA, vertA, vertB, E);
        k_copyW<<<gW, TB, 0, stream>>>(vertA, vertB, V);
        k_fused_p<<<gE, TB, 0, stream>>>(permA, vertB, vertA, E);
        k_cand_p<<<gE, TB, 0, stream>>>(permA, permB, vertA, flags, cand, E);
        k_conn1_p<<<gE, TB, 0, stream>>>(permA, flags, pack, E);
        k_conn2_p<<<gE, TB, 0, stream>>>(permA, flags, pack, E);
        k_collapse_p<<<gE, TB, 0, stream>>>(permA, cand, flags, pack, vin,
                                            repl, vout, E);
    } else {
        k_scatter1<<<gE, TB, 0, stream>>>(edges, pri, vertA, E);
        k_copyW<<<gW, TB, 0, stream>>>(vertB, vertA, V);
        k_fused<<<gE, TB, 0, stream>>>(edges, vertA, vertB, E);
        k_copyW<<<gW, TB, 0, stream>>>(vertA, vertB, V);
        k_fused<<<gE, TB, 0, stream>>>(edges, vertB, vertA, E);
        k_cand<<<gE, TB, 0, stream>>>(edges, pri, vertA, flags, cand, E);
        k_conn1<<<gE, TB, 0, stream>>>(edges, flags, pack, E);
        k_conn2<<<gE, TB, 0, stream>>>(edges, flags, pack, E);
        k_collapse<<<gE, TB, 0, stream>>>(edges, cand, flags, pack, vin,
                                          repl, vout, E);
    }
    k_faces<<<gF, TB, 0, stream>>>(faces, repl, fout, F);
}

// Round 12
// 1385.603 us; speedup vs baseline: 1.2405x; 1.2405x over previous
//
#include <hip/hip_runtime.h>
#include <math.h>

typedef unsigned long long u64;
typedef unsigned int u32;

// key = (f32 bits of priority << 23) | edge index. Order-isomorphic to the
// reference's stable-argsort rank (p >= 0 -> bits value-monotone; index
// breaks ties exactly like stable argsort). E < 2^23.
__device__ __forceinline__ u64 mkkey(float p, int e) {
    return ((u64)__float_as_uint(p) << 23) | (unsigned)e;
}
__device__ __forceinline__ u64 umax64(u64 a, u64 b) { return a > b ? a : b; }

// nontemporal 8B edge load (streaming; don't evict vert lines from L2)
__device__ __forceinline__ int2 ldnt_edge(const int2* p, int e) {
    u64 v = __builtin_nontemporal_load((const u64*)p + e);
    int2 r; r.x = (int)(v & 0xFFFFFFFFu); r.y = (int)(v >> 32);
    return r;
}

__global__ void k_sentinel(float* out, float v) {
    if (threadIdx.x == 0 && blockIdx.x == 0) out[0] = v;
}
__global__ void k_zero16(uint4* __restrict__ p, int n) {
    int i = blockIdx.x * blockDim.x + threadIdx.x;
    if (i < n) p[i] = make_uint4(0, 0, 0, 0);
}
__global__ void k_copyW(u64* __restrict__ dst, const u64* __restrict__ src, int n) {
    int i = blockIdx.x * blockDim.x + threadIdx.x;
    if (i < n) dst[i] = src[i];
}

// iter1: vert = max(vert, key) at both endpoints; read-filter (vert monotone,
// stale reads only ever smaller -> skip is conservative-correct).
__global__ void k_scatter1(const int2* __restrict__ edges, const float* __restrict__ pri,
                           u64* __restrict__ vert, int E) {
    int e = blockIdx.x * blockDim.x + threadIdx.x;
    if (e >= E) return;
    u64 k = mkkey(__builtin_nontemporal_load(pri + e), e);
    int2 ed = ldnt_edge(edges, e);
    u64 a = vert[ed.x], b = vert[ed.y];
    if (k > a) atomicMax(&vert[ed.x], k);
    if (k > b) atomicMax(&vert[ed.y], k);
}

// ref iterations 2,3 (Jacobi, double buffer; vdst pre-copied from vsrc):
// er = max(vsrc[x],vsrc[y]); vdst = max(vdst, er) at both endpoints.
__global__ void k_fused(const int2* __restrict__ edges, const u64* __restrict__ vsrc,
                        u64* __restrict__ vdst, int E) {
    int e = blockIdx.x * blockDim.x + threadIdx.x;
    if (e >= E) return;
    int2 ed = ldnt_edge(edges, e);
    u64 a = vsrc[ed.x], b = vsrc[ed.y];
    u64 er = umax64(a, b);
    if (er > a) atomicMax(&vdst[ed.x], er);
    if (er > b) atomicMax(&vdst[ed.y], er);
}

// final gather + cand test. cand edges form a matching (unique keys, strict
// local maxima) -> single writer per vertex -> plain stores.
// flags bit0 = connA (1 at c0), bit1 = markC (set-0 position: c0 and c1)
__global__ void k_cand(const int2* __restrict__ edges, const float* __restrict__ pri,
                       const u64* __restrict__ vert, unsigned char* __restrict__ flags,
                       unsigned char* __restrict__ cand, int E) {
    int e = blockIdx.x * blockDim.x + threadIdx.x;
    if (e >= E) return;
    int2 ed = ldnt_edge(edges, e);
    u64 er = umax64(vert[ed.x], vert[ed.y]);
    float p = __builtin_nontemporal_load(pri + e);
    bool c = (er == mkkey(p, e)) && (p > 0.0f);
    __builtin_nontemporal_store((unsigned char)(c ? 1 : 0), cand + e);
    if (c) { flags[ed.x] = 3; if (ed.y != ed.x) flags[ed.y] = 2; }
}

// add round 1 into pack lo16: ec = A[x]+A[y]
__global__ void k_conn1(const int2* __restrict__ edges, const unsigned char* __restrict__ flags,
                        u32* __restrict__ pack, int E) {
    int e = blockIdx.x * blockDim.x + threadIdx.x;
    if (e >= E) return;
    int2 ed = ldnt_edge(edges, e);
    u32 ec = (u32)(flags[ed.x] & 1) + (u32)(flags[ed.y] & 1);
    if (ec) { atomicAdd(&pack[ed.x], ec); atomicAdd(&pack[ed.y], ec); }
}

// add round 2 into pack hi16; set-0 applied at read via markC bit.
// lo16 stable during this kernel (only <<16 adds; sums << 2^16, no carry).
__global__ void k_conn2(const int2* __restrict__ edges, const unsigned char* __restrict__ flags,
                        u32* __restrict__ pack, int E) {
    int e = blockIdx.x * blockDim.x + threadIdx.x;
    if (e >= E) return;
    int2 ed = ldnt_edge(edges, e);
    unsigned char gx = flags[ed.x], gy = flags[ed.y];
    u32 fx = (gx & 2) ? 0u : ((u32)(gx & 1) + (pack[ed.x] & 0xFFFFu));
    u32 fy = (gy & 2) ? 0u : ((u32)(gy & 1) + (pack[ed.y] & 0xFFFFu));
    u32 ec = fx + fy;
    if (ec) { atomicAdd(&pack[ed.x], ec << 16); atomicAdd(&pack[ed.y], ec << 16); }
}

// collapse: memoized cand early-out; final conn[e1]=(markC?0:A+lo)+hi; if <=2:
// repl[e1]=e0+1, vout[e0]=f32 midpoint (matching -> race-free).
__global__ void k_collapse(const int2* __restrict__ edges, const unsigned char* __restrict__ cand,
                           const unsigned char* __restrict__ flags,
                           const u32* __restrict__ pack, const float* __restrict__ vin,
                           int* __restrict__ repl, float* __restrict__ vout, int E) {
    int e = blockIdx.x * blockDim.x + threadIdx.x;
    if (e >= E) return;
    if (!__builtin_nontemporal_load(cand + e)) return;
    int2 ed = edges[e];
    unsigned char gy = flags[ed.y];
    u32 py = pack[ed.y];
    u32 fy = (gy & 2) ? 0u : ((u32)(gy & 1) + (py & 0xFFFFu));
    u32 total = fy + (py >> 16);
    if (total <= 2) {
        repl[ed.y] = ed.x + 1;
        size_t bx = (size_t)ed.x * 3, by = (size_t)ed.y * 3;
#pragma unroll
        for (int j = 0; j < 3; ++j)
            vout[bx + j] = 0.5f * (vin[bx + j] + vin[by + j]);
    }
}

// faces: LDS-staged coalesced AoS read/write (stride-3 scalar was uncoalesced)
#define FB 256
__global__ void k_faces(const int* __restrict__ faces, const int* __restrict__ repl,
                        float* __restrict__ fout, int F) {
    __shared__ int li[FB * 3];
    __shared__ float lo[FB * 3];
    int t = threadIdx.x;
    size_t base = (size_t)blockIdx.x * (FB * 3);
    size_t n3 = (size_t)F * 3;
#pragma unroll
    for (int j = 0; j < 3; ++j) {
        size_t g = base + j * FB + t;
        if (g < n3) li[j * FB + t] = __builtin_nontemporal_load(faces + g);
    }
    __syncthreads();
    int fidx = blockIdx.x * FB + t;
    if (fidx < F) {
        int a0 = li[3 * t], a1 = li[3 * t + 1], a2 = li[3 * t + 2];
        int r0 = repl[a0]; if (r0) a0 = r0 - 1;
        int r1 = repl[a1]; if (r1) a1 = r1 - 1;
        int r2 = repl[a2]; if (r2) a2 = r2 - 1;
        if (a0 == a1 || a1 == a2 || a0 == a2) { a0 = 0; a1 = 0; a2 = 0; }
        lo[3 * t] = (float)a0; lo[3 * t + 1] = (float)a1; lo[3 * t + 2] = (float)a2;
    }
    __syncthreads();
#pragma unroll
    for (int j = 0; j < 3; ++j) {
        size_t g = base + j * FB + t;
        if (g < n3) __builtin_nontemporal_store(lo[j * FB + t], fout + g);
    }
}

extern "C" void kernel_launch(void* const* d_in, const int* in_sizes, int n_in,
                              void* d_out, int out_size, void* d_ws, size_t ws_size,
                              hipStream_t stream) {
    const int V = in_sizes[0] / 3;
    const int F = in_sizes[1] / 3;
    const int E = in_sizes[3];

    const float* vin  = (const float*)d_in[0];
    const int* faces  = (const int*)d_in[1];
    const int2* edges = (const int2*)d_in[2];
    const float* pri  = (const float*)d_in[3];

    float* vout = (float*)d_out;                 // f32 vertices [0, 3V)
    float* fout = vout + (size_t)V * 3;          // f32 face ids [3V, 3V+3F)

    // ws (~56MB): zero span [vertA(16M) flags(2M) pack(8M) repl(8M)]
    //             then vertB(16M) cand(6M)
    char* ws = (char*)d_ws;
    size_t off = 0;
    auto alloc = [&](size_t n) -> void* {
        void* p = ws + off;
        off = (off + n + 255) & ~(size_t)255;
        return p;
    };
    u64* vertA           = (u64*)alloc((size_t)V * 8);
    unsigned char* flags = (unsigned char*)alloc((size_t)V);
    u32* pack            = (u32*)alloc((size_t)V * 4);
    int* repl            = (int*)alloc((size_t)V * 4);
    size_t zero_bytes = off;
    u64* vertB           = (u64*)alloc((size_t)V * 8);
    unsigned char* cand  = (unsigned char*)alloc((size_t)E);
    size_t needed = off;

    const int TB = 256;
    if (ws_size > 0 && ws_size < needed) {
        k_sentinel<<<1, 64, 0, stream>>>(vout, ldexpf(1.0f, (int)(ws_size >> 23)));
        return;
    }

    const int gE = (E + TB - 1) / TB;
    const int gF = (F + FB - 1) / FB;
    const int gW = (V + TB - 1) / TB;
    const int nZ = (int)(zero_bytes / 16);
    const int gZ = (nZ + TB - 1) / TB;

    k_zero16<<<gZ, TB, 0, stream>>>((uint4*)ws, nZ);
    // vertices pass through (f32), collapsed heads overwritten later
    hipMemcpyAsync(d_out, d_in[0], (size_t)V * 3 * sizeof(float),
                   hipMemcpyDeviceToDevice, stream);

    // iter1 scatter; copy+fused (iter2); copy+fused (iter3); final gather fused
    k_scatter1<<<gE, TB, 0, stream>>>(edges, pri, vertA, E);
    k_copyW<<<gW, TB, 0, stream>>>(vertB, vertA, V);
    k_fused<<<gE, TB, 0, stream>>>(edges, vertA, vertB, E);
    k_copyW<<<gW, TB, 0, stream>>>(vertA, vertB, V);
    k_fused<<<gE, TB, 0, stream>>>(edges, vertB, vertA, E);
    k_cand<<<gE, TB, 0, stream>>>(edges, pri, vertA, flags, cand, E);

    k_conn1<<<gE, TB, 0, stream>>>(edges, flags, pack, E);
    k_conn2<<<gE, TB, 0, stream>>>(edges, flags, pack, E);

    k_collapse<<<gE, TB, 0, stream>>>(edges, cand, flags, pack, vin,
                                      repl, vout, E);
    k_faces<<<gF, FB, 0, stream>>>(faces, repl, fout, F);
}